// Round 9
// baseline (504.826 us; speedup 1.0000x reference)
//
#include <hip/hip_runtime.h>
#include <math.h>

#define N_NODES 50000
#define N_EDGES 800000
#define NODE_IN 36
#define EDGE_IN 16
#define C_HID 128
#define C_OUT 64
#define BN_EPS 1e-5f
#define DT_NT 32    // nodes per block in dense tiled kernels
#define ZSTR 136    // bf16 LDS row stride for 128-wide tiles
#define ZS1 72      // bf16 LDS row stride for 64-wide (gine1) tiles

// hierarchical scan geometry
#define SB_T 512
#define SB_N ((N_NODES + SB_T - 1) / SB_T)    // 98 blocks

// k_prep block-range split (EAS folded into k_fill)
#define NF_BLOCKS ((N_NODES * NODE_IN + 255) / 256)   // 7032
#define DEG_BLOCKS ((N_EDGES + 255) / 256)            // 3125

// wtb layout: [3][128][128] (W2n^T, Wl^T, Wr^T) + [128][64] (W1n^T, k-padded)
#define WTB_MAIN (3 * C_HID * C_HID)
#define WTB_TOTAL (WTB_MAIN + C_HID * 64)

typedef __attribute__((ext_vector_type(2))) float v2f;
typedef __attribute__((ext_vector_type(8))) short s8v;   // 8 bf16 (4 VGPR) MFMA frag
typedef __attribute__((ext_vector_type(4))) float f4v;   // MFMA accumulator

__device__ __forceinline__ int rfl(int v) { return __builtin_amdgcn_readfirstlane(v); }

__device__ __forceinline__ v2f v2(float s) { v2f r; r.x = s; r.y = s; return r; }

// paired bf16: u32 = bf16(lo) | bf16(hi)<<16 ; lo = channel c, hi = channel c+64
__device__ __forceinline__ v2f unpack_bf2(unsigned u) {
    v2f r;
    r.x = __uint_as_float(u << 16);
    r.y = __uint_as_float(u & 0xFFFF0000u);
    return r;
}
__device__ __forceinline__ unsigned pack_bf2(float lo, float hi) {
    unsigned ul = __float_as_uint(lo); ul += 0x7FFF + ((ul >> 16) & 1);
    unsigned uh = __float_as_uint(hi); uh += 0x7FFF + ((uh >> 16) & 1);
    return (ul >> 16) | (uh & 0xFFFF0000u);
}
__device__ __forceinline__ ushort bf16r(float x) {
    unsigned u = __float_as_uint(x); u += 0x7FFF + ((u >> 16) & 1);
    return (ushort)(u >> 16);
}

__device__ __forceinline__ v2f sel4v(int cat, v2f a, v2f b, v2f c, v2f d) {
    v2f r = (cat == 0) ? a : b;
    r = (cat == 2) ? c : r;
    r = (cat == 3) ? d : r;
    return r;
}
__device__ __forceinline__ float sel4(int cat, float a, float b, float c, float d) {
    float r = (cat == 0) ? a : b;
    r = (cat == 2) ? c : r;
    r = (cat == 3) ? d : r;
    return r;
}

// merge two cross-lane-sum streams: lanes with (lane&off)==0 accumulate x,
// lanes with (lane&off)!=0 accumulate y; one shuffle instead of two.
__device__ __forceinline__ float merge_pair(float x, float y, int off) {
    bool hi = (threadIdx.x & off) != 0;
    float send = hi ? x : y;
    float recv = __shfl_xor(send, off);
    return (hi ? y : x) + recv;
}

// ===== fused prep: node features | degree histogram =====
__global__ void k_prep(const int* __restrict__ xcat,
                       const float* __restrict__ xcont,
                       const float* __restrict__ node_emb,
                       const int* __restrict__ ei,
                       float* __restrict__ x,
                       int* __restrict__ deg) {
    int bb = blockIdx.x;
    if (bb < NF_BLOCKS) {
        int idx = bb * 256 + threadIdx.x;
        if (idx >= N_NODES * NODE_IN) return;
        int i = idx / NODE_IN;
        int j = idx - i * NODE_IN;
        float v;
        if (j < 20) v = node_emb[xcat[i] * 20 + j];
        else        v = xcont[i * 16 + (j - 20)];
        x[idx] = v;
        return;
    }
    int e = (bb - NF_BLOCKS) * 256 + threadIdx.x;
    if (e >= N_EDGES) return;
    atomicAdd(deg + ei[N_EDGES + e], 1);
}

// weight prep: transpose + bf16-convert W2n, Wl, Wr (128k) and W1n (64k padded)
__global__ void k_wconv(const float* __restrict__ W2n, const float* __restrict__ Wl,
                        const float* __restrict__ Wr, const float* __restrict__ W1n,
                        ushort* __restrict__ wtb) {
    int idx = blockIdx.x * 256 + threadIdx.x;
    if (idx >= WTB_TOTAL) return;
    if (idx < WTB_MAIN) {
        int mm = idx >> 14;
        int r = idx & 16383;
        int n = r >> 7, k = r & 127;
        const float* src = (mm == 0) ? W2n : (mm == 1 ? Wl : Wr);
        wtb[idx] = bf16r(src[k * C_HID + n]);
    } else {
        int r = idx - WTB_MAIN;
        int n = r >> 6, k = r & 63;
        wtb[idx] = (k < NODE_IN) ? bf16r(W1n[k * C_HID + n]) : (ushort)0;
    }
}

// ===== hierarchical scan: 98-block reduce -> 1-block scan -> 98-block emit =====
__global__ void k_scan1(const int* __restrict__ deg, int* __restrict__ bsum) {
    int i = blockIdx.x * SB_T + threadIdx.x;
    int v = (i < N_NODES) ? deg[i] : 0;
#pragma unroll
    for (int off = 32; off > 0; off >>= 1) v += __shfl_xor(v, off);
    __shared__ int red[SB_T / 64];
    int wid = threadIdx.x >> 6, lane = threadIdx.x & 63;
    if (lane == 0) red[wid] = v;
    __syncthreads();
    if (threadIdx.x == 0) {
        int s = 0;
#pragma unroll
        for (int w = 0; w < SB_T / 64; w++) s += red[w];
        bsum[blockIdx.x] = s;
    }
}

__global__ void k_scan2(const int* __restrict__ bsum, int* __restrict__ boff,
                        int* __restrict__ rowp) {
    __shared__ int s[128];
    int t = threadIdx.x;
    int v = (t < SB_N) ? bsum[t] : 0;
    s[t] = v;
    __syncthreads();
    for (int off = 1; off < 128; off <<= 1) {
        int u = (t >= off) ? s[t - off] : 0;
        __syncthreads();
        s[t] += u;
        __syncthreads();
    }
    if (t < SB_N) boff[t] = s[t] - v;          // exclusive prefix
    if (t == SB_N - 1) rowp[N_NODES] = s[t];   // total (= N_EDGES)
}

__global__ void k_scan3(const int* __restrict__ deg, const int* __restrict__ boff,
                        int* __restrict__ rowp, int* __restrict__ cursor) {
    int b = blockIdx.x, t = threadIdx.x;
    int i = b * SB_T + t;
    int d = (i < N_NODES) ? deg[i] : 0;
    int lane = t & 63;
    int v = d;   // inclusive scan within wave
#pragma unroll
    for (int off = 1; off < 64; off <<= 1) {
        int u = __shfl_up(v, off);
        if (lane >= off) v += u;
    }
    __shared__ int wsum[SB_T / 64];
    int wid = t >> 6;
    if (lane == 63) wsum[wid] = v;
    __syncthreads();
    int wo = 0;
    for (int w = 0; w < wid; w++) wo += wsum[w];
    int excl = boff[b] + wo + v - d;
    if (i < N_NODES) { rowp[i] = excl; cursor[i] = excl; }
}

// fill: meta {src|cat<<24} + edge-cont copy into CSR order + ea_sum reduction
// (folded from k_prep: this kernel already reads every econt row + ecat).
__global__ void k_fill(const int* __restrict__ ei, const int* __restrict__ ecat,
                       const float* __restrict__ econt,
                       int* __restrict__ cursor, int* __restrict__ csr_ps,
                       float* __restrict__ csr_e, float* __restrict__ ea_sum) {
    int e = blockIdx.x * blockDim.x + threadIdx.x;
    float vals[16];
    if (e < N_EDGES) {
        int d = ei[N_EDGES + e];
        const float4* s4 = (const float4*)(econt + (size_t)e * 12);
        float4 a = s4[0], b = s4[1], c = s4[2];
        int cat = ecat[e];
        int pos = atomicAdd(cursor + d, 1);
        csr_ps[pos] = ei[e] | (cat << 24);
        float4* d4 = (float4*)(csr_e + (size_t)pos * 12);
        d4[0] = a; d4[1] = b; d4[2] = c;
        vals[0] = a.x;  vals[1] = a.y;  vals[2] = a.z;  vals[3] = a.w;
        vals[4] = b.x;  vals[5] = b.y;  vals[6] = b.z;  vals[7] = b.w;
        vals[8] = c.x;  vals[9] = c.y;  vals[10] = c.z; vals[11] = c.w;
        vals[12] = (cat == 0) ? 1.f : 0.f;
        vals[13] = (cat == 1) ? 1.f : 0.f;
        vals[14] = (cat == 2) ? 1.f : 0.f;
        vals[15] = (cat == 3) ? 1.f : 0.f;
    } else {
#pragma unroll
        for (int k = 0; k < 16; k++) vals[k] = 0.f;
    }
#pragma unroll
    for (int k = 0; k < 16; k++) {
        float v = vals[k];
#pragma unroll
        for (int off = 32; off > 0; off >>= 1) v += __shfl_xor(v, off);
        vals[k] = v;
    }
    __shared__ float red[4][16];
    int wid = threadIdx.x >> 6, lane = threadIdx.x & 63;
    if (lane == 0) {
#pragma unroll
        for (int k = 0; k < 16; k++) red[wid][k] = vals[k];
    }
    __syncthreads();
    if (threadIdx.x < 16) {
        float s = red[0][threadIdx.x] + red[1][threadIdx.x] +
                  red[2][threadIdx.x] + red[3][threadIdx.x];
        atomicAdd(ea_sum + threadIdx.x, s);
    }
}

// ======== GINE1 gather (F=36): 4-edge batches, CSR-ordered edge feats ========
__global__ void k_gine1_gather(const int* __restrict__ rowp,
                               const int* __restrict__ csr_ps,
                               const float* __restrict__ csr_e,
                               const float* __restrict__ edge_emb,
                               const float* __restrict__ W,   // [16,36]
                               const float* __restrict__ b,   // [36]
                               const float* __restrict__ x,
                               float* __restrict__ agg) {
    int i = blockIdx.x * 4 + (threadIdx.x >> 6);
    int lane = threadIdx.x & 63;
    if (i >= N_NODES) return;
    int c = (lane < NODE_IN) ? lane : (NODE_IN - 1);
    float w[12];
#pragma unroll
    for (int k = 0; k < 12; k++) w[k] = W[(4 + k) * NODE_IN + c];
    float tb[4];
#pragma unroll
    for (int q = 0; q < 4; q++) {
        float v = b[c];
#pragma unroll
        for (int k = 0; k < 4; k++) v += edge_emb[q * 4 + k] * W[k * NODE_IN + c];
        tb[q] = v;
    }
    int beg = rfl(rowp[i]), end = rfl(rowp[i + 1]);
    float acc = 0.f;
    int p = beg;
    for (; p + 4 <= end; p += 4) {
        int ps4[4];
        float4 A[4], B[4], C4[4];
        float xs[4];
#pragma unroll
        for (int bq = 0; bq < 4; bq++) {
            const float4* ec4 = (const float4*)(csr_e + (size_t)(p + bq) * 12);
            A[bq] = ec4[0]; B[bq] = ec4[1]; C4[bq] = ec4[2];
            ps4[bq] = rfl(csr_ps[p + bq]);
            xs[bq] = x[(size_t)(ps4[bq] & 0xFFFFFF) * NODE_IN + c];
        }
#pragma unroll
        for (int bq = 0; bq < 4; bq++) {
            int cat = ps4[bq] >> 24;
            float t = sel4(cat, tb[0], tb[1], tb[2], tb[3]);
            t += A[bq].x * w[0] + A[bq].y * w[1] + A[bq].z * w[2] + A[bq].w * w[3];
            t += B[bq].x * w[4] + B[bq].y * w[5] + B[bq].z * w[6] + B[bq].w * w[7];
            t += C4[bq].x * w[8] + C4[bq].y * w[9] + C4[bq].z * w[10] + C4[bq].w * w[11];
            acc += fmaxf(xs[bq] + t, 0.f);
        }
    }
    for (; p < end; ++p) {
        int ps = rfl(csr_ps[p]);
        int src = ps & 0xFFFFFF, cat = ps >> 24;
        const float4* ec4 = (const float4*)(csr_e + (size_t)p * 12);
        float4 A = ec4[0], B = ec4[1], C4 = ec4[2];
        float t = sel4(cat, tb[0], tb[1], tb[2], tb[3]);
        t += A.x * w[0] + A.y * w[1] + A.z * w[2] + A.w * w[3];
        t += B.x * w[4] + B.y * w[5] + B.z * w[6] + B.w * w[7];
        t += C4.x * w[8] + C4.y * w[9] + C4.z * w[10] + C4.w * w[11];
        acc += fmaxf(x[(size_t)src * NODE_IN + c] + t, 0.f);
    }
    if (lane < NODE_IN) agg[(size_t)i * NODE_IN + lane] = acc;
}

// ===== GINE1 node MLP + BN (MFMA): z bf16 in LDS (K padded 36->64),
// W1n^T bf16 from L2. Each wave owns n-tiles {2q,2q+1,2q+4,2q+5} so the
// (c, c+64) bf16 pair packs in-thread. Same verified fragment recipe as
// k_gine2_gat0 phase 2. =====
__global__ __launch_bounds__(256, 4) void k_gine1_node(
        const float* __restrict__ x, const float* __restrict__ agg,
        const float* __restrict__ eps_p,
        const ushort* __restrict__ w1t,   // [128 n][64 k] bf16 (k>=36 zero)
        const float* __restrict__ b, const float* __restrict__ g,
        const float* __restrict__ bb, const float* __restrict__ m,
        const float* __restrict__ v, unsigned* __restrict__ h1p) {
    __shared__ ushort zb[DT_NT * ZS1];   // 4.5 KB
    int tid = threadIdx.x;
    int node0 = blockIdx.x * DT_NT;
    int nmax = min(DT_NT, N_NODES - node0);
    float s = 1.f + eps_p[0];
    for (int t = tid; t < DT_NT * 64; t += 256) {
        int n = t >> 6, k = t & 63;
        float val = 0.f;
        if (n < nmax && k < NODE_IN) {
            size_t o = (size_t)(node0 + n) * NODE_IN + k;
            val = s * x[o] + agg[o];
        }
        zb[n * ZS1 + k] = bf16r(val);
    }
    __syncthreads();
    int lane = tid & 63, w = tid >> 6;
    int lo4 = lane & 15, hi4 = lane >> 4;
    int mt = w & 1, q = w >> 1;
    const ushort* zrow = &zb[(mt * 16 + lo4) * ZS1 + hi4 * 8];
    s8v afr[2];
    afr[0] = *(const s8v*)(zrow);
    afr[1] = *(const s8v*)(zrow + 32);
    f4v accL[2], accH[2];
#pragma unroll
    for (int j = 0; j < 2; j++) {
        int cL = (2 * q + j) * 16 + lo4;          // lo col 0..63
        const ushort* wrL = w1t + (size_t)cL * 64 + hi4 * 8;
        const ushort* wrH = w1t + (size_t)(cL + 64) * 64 + hi4 * 8;
        f4v aL = {0.f, 0.f, 0.f, 0.f}, aH = {0.f, 0.f, 0.f, 0.f};
#pragma unroll
        for (int ks = 0; ks < 2; ks++) {
            s8v bL = *(const s8v*)(wrL + ks * 32);
            s8v bH = *(const s8v*)(wrH + ks * 32);
            aL = __builtin_amdgcn_mfma_f32_16x16x32_bf16(afr[ks], bL, aL, 0, 0, 0);
            aH = __builtin_amdgcn_mfma_f32_16x16x32_bf16(afr[ks], bH, aH, 0, 0, 0);
        }
        accL[j] = aL; accH[j] = aH;
    }
#pragma unroll
    for (int j = 0; j < 2; j++) {
        int c = (2 * q + j) * 16 + lo4;
        float bLo = b[c], bHi = b[c + 64];
        float scLo = g[c] * rsqrtf(v[c] + BN_EPS);
        float scHi = g[c + 64] * rsqrtf(v[c + 64] + BN_EPS);
        float mLo = m[c], mHi = m[c + 64];
        float beLo = bb[c], beHi = bb[c + 64];
#pragma unroll
        for (int r = 0; r < 4; r++) {
            int i = node0 + mt * 16 + hi4 * 4 + r;
            if (i < N_NODES) {
                float lo = (fmaxf(accL[j][r] + bLo, 0.f) - mLo) * scLo + beLo;
                float hi = (fmaxf(accH[j][r] + bHi, 0.f) - mHi) * scHi + beHi;
                h1p[(size_t)i * 64 + c] = pack_bf2(lo, hi);
            }
        }
    }
}

// ======== GINE2 gather: 4-edge batches, paired bf16 h1, CSR edge feats ========
__global__ void k_gine2_gather(const int* __restrict__ rowp,
                               const int* __restrict__ csr_ps,
                               const float* __restrict__ csr_e,
                               const float* __restrict__ edge_emb,
                               const float* __restrict__ W,   // [16,128]
                               const float* __restrict__ b,   // [128]
                               const unsigned* __restrict__ h1p,
                               float2* __restrict__ aggp) {
    int i = blockIdx.x * 4 + (threadIdx.x >> 6);
    int lane = threadIdx.x & 63;
    if (i >= N_NODES) return;
    v2f w01[12];
#pragma unroll
    for (int k = 0; k < 12; k++) {
        w01[k].x = W[(4 + k) * C_HID + lane];
        w01[k].y = W[(4 + k) * C_HID + lane + 64];
    }
    v2f tb01[4];
#pragma unroll
    for (int q = 0; q < 4; q++) {
        v2f t; t.x = b[lane]; t.y = b[lane + 64];
#pragma unroll
        for (int k = 0; k < 4; k++) {
            float ev = edge_emb[q * 4 + k];
            t.x += ev * W[k * C_HID + lane];
            t.y += ev * W[k * C_HID + lane + 64];
        }
        tb01[q] = t;
    }
    const v2f zero = v2(0.f);
    int beg = rfl(rowp[i]), end = rfl(rowp[i + 1]);
    v2f acc01 = zero;
    int p = beg;
    for (; p + 4 <= end; p += 4) {
        int ps4[4];
        float4 A[4], B[4], C4[4];
        v2f xs[4];
#pragma unroll
        for (int bq = 0; bq < 4; bq++) {
            const float4* ec4 = (const float4*)(csr_e + (size_t)(p + bq) * 12);
            A[bq] = ec4[0]; B[bq] = ec4[1]; C4[bq] = ec4[2];
            ps4[bq] = rfl(csr_ps[p + bq]);
            xs[bq] = unpack_bf2(h1p[(size_t)(ps4[bq] & 0xFFFFFF) * 64 + lane]);
        }
#pragma unroll
        for (int bq = 0; bq < 4; bq++) {
            int cat = ps4[bq] >> 24;
            v2f t = sel4v(cat, tb01[0], tb01[1], tb01[2], tb01[3]);
            t = __builtin_elementwise_fma(v2(A[bq].x), w01[0], t);
            t = __builtin_elementwise_fma(v2(A[bq].y), w01[1], t);
            t = __builtin_elementwise_fma(v2(A[bq].z), w01[2], t);
            t = __builtin_elementwise_fma(v2(A[bq].w), w01[3], t);
            t = __builtin_elementwise_fma(v2(B[bq].x), w01[4], t);
            t = __builtin_elementwise_fma(v2(B[bq].y), w01[5], t);
            t = __builtin_elementwise_fma(v2(B[bq].z), w01[6], t);
            t = __builtin_elementwise_fma(v2(B[bq].w), w01[7], t);
            t = __builtin_elementwise_fma(v2(C4[bq].x), w01[8], t);
            t = __builtin_elementwise_fma(v2(C4[bq].y), w01[9], t);
            t = __builtin_elementwise_fma(v2(C4[bq].z), w01[10], t);
            t = __builtin_elementwise_fma(v2(C4[bq].w), w01[11], t);
            acc01 += __builtin_elementwise_max(xs[bq] + t, zero);
        }
    }
    for (; p < end; ++p) {
        int ps = rfl(csr_ps[p]);
        int src = ps & 0xFFFFFF, cat = ps >> 24;
        const float4* ec4 = (const float4*)(csr_e + (size_t)p * 12);
        float4 A = ec4[0], B = ec4[1], C4 = ec4[2];
        v2f xs = unpack_bf2(h1p[(size_t)src * 64 + lane]);
        v2f t = sel4v(cat, tb01[0], tb01[1], tb01[2], tb01[3]);
        t = __builtin_elementwise_fma(v2(A.x), w01[0], t);
        t = __builtin_elementwise_fma(v2(A.y), w01[1], t);
        t = __builtin_elementwise_fma(v2(A.z), w01[2], t);
        t = __builtin_elementwise_fma(v2(A.w), w01[3], t);
        t = __builtin_elementwise_fma(v2(B.x), w01[4], t);
        t = __builtin_elementwise_fma(v2(B.y), w01[5], t);
        t = __builtin_elementwise_fma(v2(B.z), w01[6], t);
        t = __builtin_elementwise_fma(v2(B.w), w01[7], t);
        t = __builtin_elementwise_fma(v2(C4.x), w01[8], t);
        t = __builtin_elementwise_fma(v2(C4.y), w01[9], t);
        t = __builtin_elementwise_fma(v2(C4.z), w01[10], t);
        t = __builtin_elementwise_fma(v2(C4.w), w01[11], t);
        acc01 += __builtin_elementwise_max(xs + t, zero);
    }
    float2 o; o.x = acc01.x; o.y = acc01.y;
    aggp[(size_t)i * 64 + lane] = o;
}

// ===== FUSED (MFMA): GINE2 node MLP+BN -> h2 in LDS (bf16) -> GAT xl/xr. =====
__global__ __launch_bounds__(256, 4) void k_gine2_gat0(
        const unsigned* __restrict__ h1p, const float2* __restrict__ aggp,
        const float* __restrict__ eps_p,
        const ushort* __restrict__ wtb,   // [3][128n][128k] bf16: W2n^T, Wl^T, Wr^T
        const float* __restrict__ b, const float* __restrict__ g,
        const float* __restrict__ bb, const float* __restrict__ bnm,
        const float* __restrict__ bnv,
        const float* __restrict__ bl, const float* __restrict__ br,
        const float* __restrict__ ea_sum, const float* __restrict__ edge_emb,
        const float* __restrict__ We,
        unsigned* __restrict__ xlp, float2* __restrict__ xrp,
        float* __restrict__ ee_loop) {
    __shared__ ushort zb[DT_NT * ZSTR];   // 8.7 KB  z (bf16)
    __shared__ ushort hb[DT_NT * ZSTR];   // 8.7 KB  h2 (bf16)
    int tid = threadIdx.x;
    int node0 = blockIdx.x * DT_NT;
    if (blockIdx.x == 0 && tid < C_HID) {
        const float inv = 1.f / (float)N_EDGES;
        float acc = 0.f;
#pragma unroll
        for (int k = 0; k < 4; k++) {
            float s = 0.f;
#pragma unroll
            for (int q = 0; q < 4; q++) s += ea_sum[12 + q] * edge_emb[q * 4 + k];
            acc += (s * inv) * We[k * C_HID + tid];
        }
#pragma unroll
        for (int k = 0; k < 12; k++)
            acc += (ea_sum[k] * inv) * We[(4 + k) * C_HID + tid];
        ee_loop[tid] = acc;
    }
    // --- phase 1: z = (1+eps)*h1 + agg -> bf16 zb ---
    {
        int nmax = min(DT_NT, N_NODES - node0);
        float s = 1.f + eps_p[0];
        for (int t = tid; t < nmax * 64; t += 256) {
            int n = t >> 6, pp = t & 63;
            v2f h = unpack_bf2(h1p[(size_t)(node0 + n) * 64 + pp]);
            float2 a = aggp[(size_t)(node0 + n) * 64 + pp];
            unsigned pk = pack_bf2(s * h.x + a.x, s * h.y + a.y);
            zb[n * ZSTR + pp]      = (ushort)(pk & 0xFFFFu);
            zb[n * ZSTR + pp + 64] = (ushort)(pk >> 16);
        }
    }
    __syncthreads();
    int lane = tid & 63;
    int w = tid >> 6;            // wave 0..3
    int lo4 = lane & 15, hi4 = lane >> 4;
    int mt = w & 1;              // m-tile (rows mt*16..mt*16+15)
    // --- phase 2: h2 = BN(ReLU(z @ W2n + b)) -> bf16 hb ---
    {
        int ntbase = (w >> 1) * 4;
        const ushort* zrow = &zb[(mt * 16 + lo4) * ZSTR + hi4 * 8];
        s8v afr[4];
#pragma unroll
        for (int ks = 0; ks < 4; ks++) afr[ks] = *(const s8v*)(zrow + ks * 32);
#pragma unroll
        for (int j = 0; j < 4; j++) {
            int nt = ntbase + j;
            int n = nt * 16 + lo4;
            const ushort* wrow = wtb + (size_t)n * 128 + hi4 * 8;
            f4v acc = {0.f, 0.f, 0.f, 0.f};
#pragma unroll
            for (int ks = 0; ks < 4; ks++) {
                s8v bfr = *(const s8v*)(wrow + ks * 32);
                acc = __builtin_amdgcn_mfma_f32_16x16x32_bf16(afr[ks], bfr, acc, 0, 0, 0);
            }
            float bnb = b[n];
            float sc = g[n] * rsqrtf(bnv[n] + BN_EPS);
            float mu = bnm[n], be = bb[n];
#pragma unroll
            for (int r = 0; r < 4; r++) {
                int mrow = mt * 16 + hi4 * 4 + r;
                float h2v = (fmaxf(acc[r] + bnb, 0.f) - mu) * sc + be;
                hb[mrow * ZSTR + n] = bf16r(h2v);
            }
        }
    }
    __syncthreads();
    // --- phase 3: xl = h2@Wl + bl (bf16 pairs), xr = h2@Wr + br (f32 pairs) ---
    {
        int pg = w >> 1;         // pair group: cols pg*32..pg*32+31 (+64 partners)
        const ushort* hrow = &hb[(mt * 16 + lo4) * ZSTR + hi4 * 8];
        s8v afr[4];
#pragma unroll
        for (int ks = 0; ks < 4; ks++) afr[ks] = *(const s8v*)(hrow + ks * 32);
        for (int wsel = 0; wsel < 2; wsel++) {
            const ushort* wt = wtb + (size_t)(1 + wsel) * C_HID * C_HID;
            const float* bm = wsel ? br : bl;
            f4v accA[2], accB[2];
#pragma unroll
            for (int j = 0; j < 2; j++) {
                int cA = (pg * 2 + j) * 16 + lo4;
                const ushort* wrA = wt + (size_t)cA * 128 + hi4 * 8;
                const ushort* wrB = wt + (size_t)(cA + 64) * 128 + hi4 * 8;
                f4v aA = {0.f, 0.f, 0.f, 0.f}, aB = {0.f, 0.f, 0.f, 0.f};
#pragma unroll
                for (int ks = 0; ks < 4; ks++) {
                    s8v bA = *(const s8v*)(wrA + ks * 32);
                    s8v bB = *(const s8v*)(wrB + ks * 32);
                    aA = __builtin_amdgcn_mfma_f32_16x16x32_bf16(afr[ks], bA, aA, 0, 0, 0);
                    aB = __builtin_amdgcn_mfma_f32_16x16x32_bf16(afr[ks], bB, aB, 0, 0, 0);
                }
                accA[j] = aA; accB[j] = aB;
            }
#pragma unroll
            for (int j = 0; j < 2; j++) {
                int c = (pg * 2 + j) * 16 + lo4;
                float blo = bm[c], bhi = bm[c + 64];
#pragma unroll
                for (int r = 0; r < 4; r++) {
                    int i = node0 + mt * 16 + hi4 * 4 + r;
                    if (i < N_NODES) {
                        float lo = accA[j][r] + blo, hi = accB[j][r] + bhi;
                        if (wsel == 0) {
                            xlp[(size_t)i * 64 + c] = pack_bf2(lo, hi);
                        } else {
                            float2 o; o.x = lo; o.y = hi;
                            xrp[(size_t)i * 64 + c] = o;
                        }
                    }
                }
            }
        }
    }
}

// ===== GAT fused: 4-edge batches, CSR edge feats, merge-network softmax =====
__global__ void k_gat_fused(const int* __restrict__ rowp,
                            const int* __restrict__ csr_ps,
                            const float* __restrict__ csr_e,
                            const float* __restrict__ edge_emb,
                            const float* __restrict__ We,    // [16,128]
                            const float* __restrict__ att,   // [128]
                            const float* __restrict__ ee_loop,
                            const unsigned* __restrict__ xlp,
                            const float2* __restrict__ xrp,
                            const float* __restrict__ bias,  // [64]
                            float* __restrict__ out) {
    int i = blockIdx.x * 4 + (threadIdx.x >> 6);
    int lane = threadIdx.x & 63;
    if (i >= N_NODES) return;
    v2f w01[12];
#pragma unroll
    for (int k = 0; k < 12; k++) {
        w01[k].x = We[(4 + k) * C_HID + lane];
        w01[k].y = We[(4 + k) * C_HID + lane + 64];
    }
    v2f tb01[4];
#pragma unroll
    for (int q = 0; q < 4; q++) {
        v2f t = v2(0.f);
#pragma unroll
        for (int k = 0; k < 4; k++) {
            float ev = edge_emb[q * 4 + k];
            t.x += ev * We[k * C_HID + lane];
            t.y += ev * We[k * C_HID + lane + 64];
        }
        tb01[q] = t;
    }
    v2f at01; at01.x = att[lane]; at01.y = att[lane + 64];
    v2f lp01; lp01.x = ee_loop[lane]; lp01.y = ee_loop[lane + 64];
    const v2f zero = v2(0.f);
    const v2f fifth = v2(0.2f);

    float2 xr2 = xrp[(size_t)i * 64 + lane];
    v2f xr01; xr01.x = xr2.x; xr01.y = xr2.y;
    v2f xld01 = unpack_bf2(xlp[(size_t)i * 64 + lane]);

    // self-loop alpha (plain exp — alphas bounded, fp32-safe; verified R8)
    v2f z01 = xld01 + xr01 + lp01;
    z01 = __builtin_elementwise_max(z01, zero) +
          fifth * __builtin_elementwise_min(z01, zero);
    v2f d01 = z01 * at01;
    // 2-value merge reduce: even lanes hold sum(x), odd lanes sum(y)
    {
        float mq = merge_pair(d01.x, d01.y, 1);
        mq += __shfl_xor(mq, 2);
        mq += __shfl_xor(mq, 4);
        mq += __shfl_xor(mq, 8);
        mq += __shfl_xor(mq, 16);
        mq += __shfl_xor(mq, 32);
        int emqi = __float_as_int(__expf(mq));
        d01.x = __int_as_float(__builtin_amdgcn_readlane(emqi, 0));
        d01.y = __int_as_float(__builtin_amdgcn_readlane(emqi, 1));
    }
    v2f den01 = d01;
    v2f acc01 = xld01 * den01;

    int beg = rfl(rowp[i]), end = rfl(rowp[i + 1]);
    int p = beg;
    for (; p + 4 <= end; p += 4) {
        int ps4[4];
        float4 A[4], B[4], C4[4];
        v2f xs[4];
#pragma unroll
        for (int bq = 0; bq < 4; bq++) {
            const float4* ec4 = (const float4*)(csr_e + (size_t)(p + bq) * 12);
            A[bq] = ec4[0]; B[bq] = ec4[1]; C4[bq] = ec4[2];
            ps4[bq] = rfl(csr_ps[p + bq]);
            xs[bq] = unpack_bf2(xlp[(size_t)(ps4[bq] & 0xFFFFFF) * 64 + lane]);
        }
        v2f dd[4];
#pragma unroll
        for (int bq = 0; bq < 4; bq++) {
            int cat = ps4[bq] >> 24;
            v2f e = sel4v(cat, tb01[0], tb01[1], tb01[2], tb01[3]);
            e = __builtin_elementwise_fma(v2(A[bq].x), w01[0], e);
            e = __builtin_elementwise_fma(v2(A[bq].y), w01[1], e);
            e = __builtin_elementwise_fma(v2(A[bq].z), w01[2], e);
            e = __builtin_elementwise_fma(v2(A[bq].w), w01[3], e);
            e = __builtin_elementwise_fma(v2(B[bq].x), w01[4], e);
            e = __builtin_elementwise_fma(v2(B[bq].y), w01[5], e);
            e = __builtin_elementwise_fma(v2(B[bq].z), w01[6], e);
            e = __builtin_elementwise_fma(v2(B[bq].w), w01[7], e);
            e = __builtin_elementwise_fma(v2(C4[bq].x), w01[8], e);
            e = __builtin_elementwise_fma(v2(C4[bq].y), w01[9], e);
            e = __builtin_elementwise_fma(v2(C4[bq].z), w01[10], e);
            e = __builtin_elementwise_fma(v2(C4[bq].w), w01[11], e);
            v2f z = xs[bq] + xr01 + e;
            z = __builtin_elementwise_max(z, zero) +
                fifth * __builtin_elementwise_min(z, zero);
            dd[bq] = z * at01;
        }
        // 8-value merge-reduce network: after 3 merge + 3 butterfly stages,
        // lane l holds the full 64-lane sum of value (l&7).
        float m01 = merge_pair(dd[0].x, dd[0].y, 1);
        float m23 = merge_pair(dd[1].x, dd[1].y, 1);
        float m45 = merge_pair(dd[2].x, dd[2].y, 1);
        float m67 = merge_pair(dd[3].x, dd[3].y, 1);
        float n0 = merge_pair(m01, m23, 2);
        float n1 = merge_pair(m45, m67, 2);
        float q = merge_pair(n0, n1, 4);
        q += __shfl_xor(q, 8);
        q += __shfl_xor(q, 16);
        q += __shfl_xor(q, 32);
        int eqi = __float_as_int(__expf(q));   // one exp covers all 8 sums
        v2f p0, p1, p2, p3;
        p0.x = __int_as_float(__builtin_amdgcn_readlane(eqi, 0));
        p0.y = __int_as_float(__builtin_amdgcn_readlane(eqi, 1));
        p1.x = __int_as_float(__builtin_amdgcn_readlane(eqi, 2));
        p1.y = __int_as_float(__builtin_amdgcn_readlane(eqi, 3));
        p2.x = __int_as_float(__builtin_amdgcn_readlane(eqi, 4));
        p2.y = __int_as_float(__builtin_amdgcn_readlane(eqi, 5));
        p3.x = __int_as_float(__builtin_amdgcn_readlane(eqi, 6));
        p3.y = __int_as_float(__builtin_amdgcn_readlane(eqi, 7));
        den01 += (p0 + p1) + (p2 + p3);
        acc01 = __builtin_elementwise_fma(p0, xs[0], acc01);
        acc01 = __builtin_elementwise_fma(p1, xs[1], acc01);
        acc01 = __builtin_elementwise_fma(p2, xs[2], acc01);
        acc01 = __builtin_elementwise_fma(p3, xs[3], acc01);
    }
    for (; p < end; ++p) {
        int ps = rfl(csr_ps[p]);
        int src = ps & 0xFFFFFF, cat = ps >> 24;
        const float4* ec4 = (const float4*)(csr_e + (size_t)p * 12);
        float4 A = ec4[0], B = ec4[1], C4 = ec4[2];
        v2f xs = unpack_bf2(xlp[(size_t)src * 64 + lane]);
        v2f e = sel4v(cat, tb01[0], tb01[1], tb01[2], tb01[3]);
        e = __builtin_elementwise_fma(v2(A.x), w01[0], e);
        e = __builtin_elementwise_fma(v2(A.y), w01[1], e);
        e = __builtin_elementwise_fma(v2(A.z), w01[2], e);
        e = __builtin_elementwise_fma(v2(A.w), w01[3], e);
        e = __builtin_elementwise_fma(v2(B.x), w01[4], e);
        e = __builtin_elementwise_fma(v2(B.y), w01[5], e);
        e = __builtin_elementwise_fma(v2(B.z), w01[6], e);
        e = __builtin_elementwise_fma(v2(B.w), w01[7], e);
        e = __builtin_elementwise_fma(v2(C4.x), w01[8], e);
        e = __builtin_elementwise_fma(v2(C4.y), w01[9], e);
        e = __builtin_elementwise_fma(v2(C4.z), w01[10], e);
        e = __builtin_elementwise_fma(v2(C4.w), w01[11], e);
        v2f z = xs + xr01 + e;
        z = __builtin_elementwise_max(z, zero) +
            fifth * __builtin_elementwise_min(z, zero);
        v2f a = z * at01;
        float mq = merge_pair(a.x, a.y, 1);
        mq += __shfl_xor(mq, 2);
        mq += __shfl_xor(mq, 4);
        mq += __shfl_xor(mq, 8);
        mq += __shfl_xor(mq, 16);
        mq += __shfl_xor(mq, 32);
        int emqi = __float_as_int(__expf(mq));
        v2f pe;
        pe.x = __int_as_float(__builtin_amdgcn_readlane(emqi, 0));
        pe.y = __int_as_float(__builtin_amdgcn_readlane(emqi, 1));
        den01 += pe;
        acc01 = __builtin_elementwise_fma(pe, xs, acc01);
    }
    out[(size_t)i * C_OUT + lane] =
        0.5f * (acc01.x / den01.x + acc01.y / den01.y) + bias[lane];
}

extern "C" void kernel_launch(void* const* d_in, const int* in_sizes, int n_in,
                              void* d_out, int out_size, void* d_ws, size_t ws_size,
                              hipStream_t stream) {
    const int*   x_cat    = (const int*)d_in[0];
    const float* x_cont   = (const float*)d_in[1];
    const int*   e_cat    = (const int*)d_in[2];
    const float* e_cont   = (const float*)d_in[3];
    const int*   ei       = (const int*)d_in[4];
    const float* node_emb = (const float*)d_in[5];
    const float* edge_emb = (const float*)d_in[6];
    const float* eps1     = (const float*)d_in[7];
    const float* W1e      = (const float*)d_in[8];
    const float* b1e      = (const float*)d_in[9];
    const float* W1n      = (const float*)d_in[10];
    const float* b1n      = (const float*)d_in[11];
    const float* g1       = (const float*)d_in[12];
    const float* bb1      = (const float*)d_in[13];
    const float* m1       = (const float*)d_in[14];
    const float* v1       = (const float*)d_in[15];
    const float* eps2     = (const float*)d_in[16];
    const float* W2e      = (const float*)d_in[17];
    const float* b2e      = (const float*)d_in[18];
    const float* W2n      = (const float*)d_in[19];
    const float* b2n      = (const float*)d_in[20];
    const float* g2       = (const float*)d_in[21];
    const float* bb2      = (const float*)d_in[22];
    const float* m2       = (const float*)d_in[23];
    const float* v2p      = (const float*)d_in[24];
    const float* Wl       = (const float*)d_in[25];
    const float* bl       = (const float*)d_in[26];
    const float* Wr       = (const float*)d_in[27];
    const float* br       = (const float*)d_in[28];
    const float* Weg      = (const float*)d_in[29];
    const float* att      = (const float*)d_in[30];
    const float* gbias    = (const float*)d_in[31];

    const size_t NF128 = (size_t)N_NODES * C_HID;

    // layout: A (fp32, x) | B (fp32, agg36 / agg-pairs / xr-pairs) |
    //         Hb (bf16 pairs) | ea_sum | ee_loop | wtb (bf16 weights) | csr_e | meta
    float* A = (float*)d_ws;                 // N*128 floats
    float* B = A + NF128;                    // N*128 floats
    unsigned* Hb = (unsigned*)(B + NF128);   // N*64 u32
    float* ea_sum  = (float*)(Hb + (size_t)N_NODES * 64);   // 16
    float* ee_loop = ea_sum + 16;            // 128
    ushort* wtb  = (ushort*)(ee_loop + C_HID);              // WTB_TOTAL bf16
    float* csr_e = (float*)(wtb + WTB_TOTAL);               // E*12 floats (16B aligned)
    int* csr_ps  = (int*)(csr_e + (size_t)N_EDGES * 12);    // E
    int* deg     = csr_ps + N_EDGES;         // N
    int* cursor  = deg + N_NODES;            // N
    int* rowp    = cursor + N_NODES;         // N+1
    int* bsum    = rowp + N_NODES + 1;       // SB_N
    int* boff    = bsum + SB_N;              // SB_N

    float* x = A;
    float* agg36 = B;
    float2* aggp = (float2*)B;    // N*64 float2
    float2* xrp  = (float2*)B;    // aliased with aggp: same node range, read-then-write in fused kernel
    unsigned* h1p = Hb; unsigned* xlp = Hb;

    size_t need = (size_t)((char*)(boff + SB_N) - (char*)d_ws);
    if (ws_size < need) return;

    hipMemsetAsync(deg, 0, N_NODES * sizeof(int), stream);
    hipMemsetAsync(ea_sum, 0, 16 * sizeof(float), stream);

    const int EB = (N_EDGES + 255) / 256;
    const int NB4 = (N_NODES + 3) / 4;
    const int NBD = (N_NODES + DT_NT - 1) / DT_NT;
    const int WB = (WTB_TOTAL + 255) / 256;

    k_wconv<<<WB, 256, 0, stream>>>(W2n, Wl, Wr, W1n, wtb);
    k_prep<<<NF_BLOCKS + DEG_BLOCKS, 256, 0, stream>>>(
        x_cat, x_cont, node_emb, ei, x, deg);
    k_scan1<<<SB_N, SB_T, 0, stream>>>(deg, bsum);
    k_scan2<<<1, 128, 0, stream>>>(bsum, boff, rowp);
    k_scan3<<<SB_N, SB_T, 0, stream>>>(deg, boff, rowp, cursor);
    k_fill<<<EB, 256, 0, stream>>>(ei, e_cat, e_cont, cursor, csr_ps, csr_e, ea_sum);

    k_gine1_gather<<<NB4, 256, 0, stream>>>(
        rowp, csr_ps, csr_e, edge_emb, W1e, b1e, x, agg36);
    k_gine1_node<<<NBD, 256, 0, stream>>>(
        x, agg36, eps1, wtb + WTB_MAIN, b1n, g1, bb1, m1, v1, h1p);
    k_gine2_gather<<<NB4, 256, 0, stream>>>(
        rowp, csr_ps, csr_e, edge_emb, W2e, b2e, h1p, aggp);

    k_gine2_gat0<<<NBD, 256, 0, stream>>>(
        h1p, aggp, eps2, wtb, b2n, g2, bb2, m2, v2p,
        bl, br, ea_sum, edge_emb, Weg, xlp, xrp, ee_loop);

    k_gat_fused<<<NB4, 256, 0, stream>>>(
        rowp, csr_ps, csr_e, edge_emb, Weg, att, ee_loop,
        xlp, xrp, gbias, (float*)d_out);
}

// Round 10
// 486.905 us; speedup vs baseline: 1.0368x; 1.0368x over previous
//
#include <hip/hip_runtime.h>
#include <math.h>

#define N_NODES 50000
#define N_EDGES 800000
#define NODE_IN 36
#define EDGE_IN 16
#define C_HID 128
#define C_OUT 64
#define BN_EPS 1e-5f
#define DT_NT 32    // nodes per block in dense tiled kernels
#define ZSTR 136    // bf16 LDS row stride (padded)

// hierarchical scan geometry
#define SB_T 512
#define SB_N ((N_NODES + SB_T - 1) / SB_T)    // 98 blocks

// k_prep block-range split
#define NF_BLOCKS ((N_NODES * NODE_IN + 255) / 256)   // 7032
#define DEG_BLOCKS ((N_EDGES + 255) / 256)            // 3125
#define EAS_BLOCKS 512

typedef __attribute__((ext_vector_type(2))) float v2f;
typedef __attribute__((ext_vector_type(8))) short s8v;   // 8 bf16 (4 VGPR) MFMA frag
typedef __attribute__((ext_vector_type(4))) float f4v;   // MFMA accumulator

__device__ __forceinline__ int rfl(int v) { return __builtin_amdgcn_readfirstlane(v); }

__device__ __forceinline__ v2f v2(float s) { v2f r; r.x = s; r.y = s; return r; }

// paired bf16: u32 = bf16(lo) | bf16(hi)<<16 ; lo = channel c, hi = channel c+64
__device__ __forceinline__ v2f unpack_bf2(unsigned u) {
    v2f r;
    r.x = __uint_as_float(u << 16);
    r.y = __uint_as_float(u & 0xFFFF0000u);
    return r;
}
__device__ __forceinline__ unsigned pack_bf2(float lo, float hi) {
    unsigned ul = __float_as_uint(lo); ul += 0x7FFF + ((ul >> 16) & 1);
    unsigned uh = __float_as_uint(hi); uh += 0x7FFF + ((uh >> 16) & 1);
    return (ul >> 16) | (uh & 0xFFFF0000u);
}
__device__ __forceinline__ ushort bf16r(float x) {
    unsigned u = __float_as_uint(x); u += 0x7FFF + ((u >> 16) & 1);
    return (ushort)(u >> 16);
}

__device__ __forceinline__ v2f sel4v(int cat, v2f a, v2f b, v2f c, v2f d) {
    v2f r = (cat == 0) ? a : b;
    r = (cat == 2) ? c : r;
    r = (cat == 3) ? d : r;
    return r;
}
__device__ __forceinline__ float sel4(int cat, float a, float b, float c, float d) {
    float r = (cat == 0) ? a : b;
    r = (cat == 2) ? c : r;
    r = (cat == 3) ? d : r;
    return r;
}

// merge two cross-lane-sum streams: lanes with (lane&off)==0 accumulate x,
// lanes with (lane&off)!=0 accumulate y; one shuffle instead of two.
__device__ __forceinline__ float merge_pair(float x, float y, int off) {
    bool hi = (threadIdx.x & off) != 0;
    float send = hi ? x : y;
    float recv = __shfl_xor(send, off);
    return (hi ? y : x) + recv;
}

// ===== fused prep: node features | degree histogram | edge-attr mean-sum =====
__global__ void k_prep(const int* __restrict__ xcat,
                       const float* __restrict__ xcont,
                       const float* __restrict__ node_emb,
                       const int* __restrict__ ei,
                       const int* __restrict__ ecat,
                       const float* __restrict__ econt,
                       float* __restrict__ x,
                       int* __restrict__ deg,
                       float* __restrict__ ea_sum) {
    int bb = blockIdx.x;
    if (bb < NF_BLOCKS) {
        int idx = bb * 256 + threadIdx.x;
        if (idx >= N_NODES * NODE_IN) return;
        int i = idx / NODE_IN;
        int j = idx - i * NODE_IN;
        float v;
        if (j < 20) v = node_emb[xcat[i] * 20 + j];
        else        v = xcont[i * 16 + (j - 20)];
        x[idx] = v;
        return;
    }
    if (bb < NF_BLOCKS + DEG_BLOCKS) {
        int e = (bb - NF_BLOCKS) * 256 + threadIdx.x;
        if (e >= N_EDGES) return;
        atomicAdd(deg + ei[N_EDGES + e], 1);
        return;
    }
    // ea_sum part
    int blk = bb - NF_BLOCKS - DEG_BLOCKS;
    float p[12];
#pragma unroll
    for (int k = 0; k < 12; k++) p[k] = 0.f;
    float cnt[4] = {0.f, 0.f, 0.f, 0.f};
    const int stride = EAS_BLOCKS * 256;
    for (int e = blk * 256 + threadIdx.x; e < N_EDGES; e += stride) {
        int c = ecat[e];
        cnt[0] += (c == 0) ? 1.f : 0.f;
        cnt[1] += (c == 1) ? 1.f : 0.f;
        cnt[2] += (c == 2) ? 1.f : 0.f;
        cnt[3] += (c == 3) ? 1.f : 0.f;
        const float4* v4 = (const float4*)(econt + (size_t)e * 12);
        float4 a = v4[0], bq = v4[1], d = v4[2];
        p[0] += a.x;  p[1] += a.y;  p[2] += a.z;  p[3] += a.w;
        p[4] += bq.x; p[5] += bq.y; p[6] += bq.z; p[7] += bq.w;
        p[8] += d.x;  p[9] += d.y;  p[10] += d.z; p[11] += d.w;
    }
    float vals[16];
#pragma unroll
    for (int k = 0; k < 12; k++) vals[k] = p[k];
#pragma unroll
    for (int k = 0; k < 4; k++) vals[12 + k] = cnt[k];
#pragma unroll
    for (int k = 0; k < 16; k++) {
        float v = vals[k];
#pragma unroll
        for (int off = 32; off > 0; off >>= 1) v += __shfl_xor(v, off);
        vals[k] = v;
    }
    __shared__ float red[4][16];
    int wid = threadIdx.x >> 6, lane = threadIdx.x & 63;
    if (lane == 0) {
#pragma unroll
        for (int k = 0; k < 16; k++) red[wid][k] = vals[k];
    }
    __syncthreads();
    if (threadIdx.x < 16) {
        float s = red[0][threadIdx.x] + red[1][threadIdx.x] +
                  red[2][threadIdx.x] + red[3][threadIdx.x];
        atomicAdd(ea_sum + threadIdx.x, s);
    }
}

// weight prep: transpose + bf16-convert W2n, Wl, Wr into wtb[m][n][k]
__global__ void k_wconv(const float* __restrict__ W2n, const float* __restrict__ Wl,
                        const float* __restrict__ Wr, ushort* __restrict__ wtb) {
    int idx = blockIdx.x * 256 + threadIdx.x;   // 3*128*128
    if (idx >= 3 * C_HID * C_HID) return;
    int mm = idx >> 14;
    int r = idx & 16383;
    int n = r >> 7, k = r & 127;
    const float* src = (mm == 0) ? W2n : (mm == 1 ? Wl : Wr);
    wtb[idx] = bf16r(src[k * C_HID + n]);
}

// ===== hierarchical scan: 98-block reduce -> 1-block scan -> 98-block emit =====
__global__ void k_scan1(const int* __restrict__ deg, int* __restrict__ bsum) {
    int i = blockIdx.x * SB_T + threadIdx.x;
    int v = (i < N_NODES) ? deg[i] : 0;
#pragma unroll
    for (int off = 32; off > 0; off >>= 1) v += __shfl_xor(v, off);
    __shared__ int red[SB_T / 64];
    int wid = threadIdx.x >> 6, lane = threadIdx.x & 63;
    if (lane == 0) red[wid] = v;
    __syncthreads();
    if (threadIdx.x == 0) {
        int s = 0;
#pragma unroll
        for (int w = 0; w < SB_T / 64; w++) s += red[w];
        bsum[blockIdx.x] = s;
    }
}

__global__ void k_scan2(const int* __restrict__ bsum, int* __restrict__ boff,
                        int* __restrict__ rowp) {
    __shared__ int s[128];
    int t = threadIdx.x;
    int v = (t < SB_N) ? bsum[t] : 0;
    s[t] = v;
    __syncthreads();
    for (int off = 1; off < 128; off <<= 1) {
        int u = (t >= off) ? s[t - off] : 0;
        __syncthreads();
        s[t] += u;
        __syncthreads();
    }
    if (t < SB_N) boff[t] = s[t] - v;          // exclusive prefix
    if (t == SB_N - 1) rowp[N_NODES] = s[t];   // total (= N_EDGES)
}

__global__ void k_scan3(const int* __restrict__ deg, const int* __restrict__ boff,
                        int* __restrict__ rowp, int* __restrict__ cursor) {
    int b = blockIdx.x, t = threadIdx.x;
    int i = b * SB_T + t;
    int d = (i < N_NODES) ? deg[i] : 0;
    int lane = t & 63;
    int v = d;   // inclusive scan within wave
#pragma unroll
    for (int off = 1; off < 64; off <<= 1) {
        int u = __shfl_up(v, off);
        if (lane >= off) v += u;
    }
    __shared__ int wsum[SB_T / 64];
    int wid = t >> 6;
    if (lane == 63) wsum[wid] = v;
    __syncthreads();
    int wo = 0;
    for (int w = 0; w < wid; w++) wo += wsum[w];
    int excl = boff[b] + wo + v - d;
    if (i < N_NODES) { rowp[i] = excl; cursor[i] = excl; }
}

// fill: meta {src|cat<<24} + edge-cont features copied into CSR order.
__global__ void k_fill(const int* __restrict__ ei, const int* __restrict__ ecat,
                       const float* __restrict__ econt,
                       int* __restrict__ cursor, int* __restrict__ csr_ps,
                       float* __restrict__ csr_e) {
    int e = blockIdx.x * blockDim.x + threadIdx.x;
    if (e >= N_EDGES) return;
    int d = ei[N_EDGES + e];
    const float4* s4 = (const float4*)(econt + (size_t)e * 12);
    float4 a = s4[0], b = s4[1], c = s4[2];
    int pos = atomicAdd(cursor + d, 1);
    csr_ps[pos] = ei[e] | (ecat[e] << 24);
    float4* d4 = (float4*)(csr_e + (size_t)pos * 12);
    d4[0] = a; d4[1] = b; d4[2] = c;
}

// ======== GINE1 gather (F=36): 4-edge batches, CSR-ordered edge feats ========
__global__ void k_gine1_gather(const int* __restrict__ rowp,
                               const int* __restrict__ csr_ps,
                               const float* __restrict__ csr_e,
                               const float* __restrict__ edge_emb,
                               const float* __restrict__ W,   // [16,36]
                               const float* __restrict__ b,   // [36]
                               const float* __restrict__ x,
                               float* __restrict__ agg) {
    int i = blockIdx.x * 4 + (threadIdx.x >> 6);
    int lane = threadIdx.x & 63;
    if (i >= N_NODES) return;
    int c = (lane < NODE_IN) ? lane : (NODE_IN - 1);
    float w[12];
#pragma unroll
    for (int k = 0; k < 12; k++) w[k] = W[(4 + k) * NODE_IN + c];
    float tb[4];
#pragma unroll
    for (int q = 0; q < 4; q++) {
        float v = b[c];
#pragma unroll
        for (int k = 0; k < 4; k++) v += edge_emb[q * 4 + k] * W[k * NODE_IN + c];
        tb[q] = v;
    }
    int beg = rfl(rowp[i]), end = rfl(rowp[i + 1]);
    float acc = 0.f;
    int p = beg;
    for (; p + 4 <= end; p += 4) {
        int ps4[4];
        float4 A[4], B[4], C4[4];
        float xs[4];
#pragma unroll
        for (int bq = 0; bq < 4; bq++) {
            const float4* ec4 = (const float4*)(csr_e + (size_t)(p + bq) * 12);
            A[bq] = ec4[0]; B[bq] = ec4[1]; C4[bq] = ec4[2];
            ps4[bq] = rfl(csr_ps[p + bq]);
            xs[bq] = x[(size_t)(ps4[bq] & 0xFFFFFF) * NODE_IN + c];
        }
#pragma unroll
        for (int bq = 0; bq < 4; bq++) {
            int cat = ps4[bq] >> 24;
            float t = sel4(cat, tb[0], tb[1], tb[2], tb[3]);
            t += A[bq].x * w[0] + A[bq].y * w[1] + A[bq].z * w[2] + A[bq].w * w[3];
            t += B[bq].x * w[4] + B[bq].y * w[5] + B[bq].z * w[6] + B[bq].w * w[7];
            t += C4[bq].x * w[8] + C4[bq].y * w[9] + C4[bq].z * w[10] + C4[bq].w * w[11];
            acc += fmaxf(xs[bq] + t, 0.f);
        }
    }
    for (; p < end; ++p) {
        int ps = rfl(csr_ps[p]);
        int src = ps & 0xFFFFFF, cat = ps >> 24;
        const float4* ec4 = (const float4*)(csr_e + (size_t)p * 12);
        float4 A = ec4[0], B = ec4[1], C4 = ec4[2];
        float t = sel4(cat, tb[0], tb[1], tb[2], tb[3]);
        t += A.x * w[0] + A.y * w[1] + A.z * w[2] + A.w * w[3];
        t += B.x * w[4] + B.y * w[5] + B.z * w[6] + B.w * w[7];
        t += C4.x * w[8] + C4.y * w[9] + C4.z * w[10] + C4.w * w[11];
        acc += fmaxf(x[(size_t)src * NODE_IN + c] + t, 0.f);
    }
    if (lane < NODE_IN) agg[(size_t)i * NODE_IN + lane] = acc;
}

// ===== GINE1 node MLP + BN; OUTPUT h1 as paired bf16 (ch c | ch c+64) =====
__global__ __launch_bounds__(256, 4) void k_gine1_node(
        const float* __restrict__ x, const float* __restrict__ agg,
        const float* __restrict__ eps_p,
        const float* __restrict__ W,   // [36,128]
        const float* __restrict__ b, const float* __restrict__ g,
        const float* __restrict__ bb, const float* __restrict__ m,
        const float* __restrict__ v, unsigned* __restrict__ h1p) {
    __shared__ float sW[NODE_IN * C_HID];     // 18 KB
    __shared__ float sz[DT_NT * NODE_IN];     // 4.5 KB
    int tid = threadIdx.x;
    int node0 = blockIdx.x * DT_NT;
    float eps = eps_p[0];
    {
        const float4* Wv = (const float4*)W;
        float4* sWv = (float4*)sW;
        for (int t = tid; t < NODE_IN * C_HID / 4; t += 256) sWv[t] = Wv[t];
    }
    {
        int nmax = min(DT_NT, N_NODES - node0);
        int tot = nmax * NODE_IN / 4;
        const float4* xv = (const float4*)(x + (size_t)node0 * NODE_IN);
        const float4* av = (const float4*)(agg + (size_t)node0 * NODE_IN);
        float4* szv = (float4*)sz;
        float s = 1.f + eps;
        for (int t = tid; t < tot; t += 256) {
            float4 a = xv[t], c = av[t];
            float4 r;
            r.x = s * a.x + c.x; r.y = s * a.y + c.y;
            r.z = s * a.z + c.z; r.w = s * a.w + c.w;
            szv[t] = r;
        }
    }
    __syncthreads();
    int cg = tid & 15, c0 = cg * 4;           // pair base (lo channels c0..c0+3)
    int n0 = (tid >> 4) * 2;                  // 2 nodes per thread
    float4 bL = *(const float4*)&b[c0];
    float4 bH = *(const float4*)&b[c0 + 64];
    float accL[2][4], accH[2][4];
#pragma unroll
    for (int n = 0; n < 2; n++) {
        accL[n][0] = bL.x; accL[n][1] = bL.y; accL[n][2] = bL.z; accL[n][3] = bL.w;
        accH[n][0] = bH.x; accH[n][1] = bH.y; accH[n][2] = bH.z; accH[n][3] = bH.w;
    }
#pragma unroll 2
    for (int jb = 0; jb < NODE_IN; jb += 4) {
#pragma unroll
        for (int r = 0; r < 4; r++) {
            float4 wl = *(const float4*)&sW[(jb + r) * C_HID + c0];
            float4 wh = *(const float4*)&sW[(jb + r) * C_HID + c0 + 64];
#pragma unroll
            for (int n = 0; n < 2; n++) {
                float zz = sz[(n0 + n) * NODE_IN + jb + r];
                accL[n][0] += zz * wl.x; accL[n][1] += zz * wl.y;
                accL[n][2] += zz * wl.z; accL[n][3] += zz * wl.w;
                accH[n][0] += zz * wh.x; accH[n][1] += zz * wh.y;
                accH[n][2] += zz * wh.z; accH[n][3] += zz * wh.w;
            }
        }
    }
    float4 gL = *(const float4*)&g[c0],  gH = *(const float4*)&g[c0 + 64];
    float4 mL = *(const float4*)&m[c0],  mH = *(const float4*)&m[c0 + 64];
    float4 vL = *(const float4*)&v[c0],  vH = *(const float4*)&v[c0 + 64];
    float4 bbL = *(const float4*)&bb[c0], bbH = *(const float4*)&bb[c0 + 64];
    float scL[4] = { gL.x * rsqrtf(vL.x + BN_EPS), gL.y * rsqrtf(vL.y + BN_EPS),
                     gL.z * rsqrtf(vL.z + BN_EPS), gL.w * rsqrtf(vL.w + BN_EPS) };
    float scH[4] = { gH.x * rsqrtf(vH.x + BN_EPS), gH.y * rsqrtf(vH.y + BN_EPS),
                     gH.z * rsqrtf(vH.z + BN_EPS), gH.w * rsqrtf(vH.w + BN_EPS) };
    float mLa[4] = { mL.x, mL.y, mL.z, mL.w }, mHa[4] = { mH.x, mH.y, mH.z, mH.w };
    float bbLa[4] = { bbL.x, bbL.y, bbL.z, bbL.w }, bbHa[4] = { bbH.x, bbH.y, bbH.z, bbH.w };
#pragma unroll
    for (int n = 0; n < 2; n++) {
        int i = node0 + n0 + n;
        if (i < N_NODES) {
            uint4 o;
            unsigned* po = (unsigned*)&o;
#pragma unroll
            for (int k = 0; k < 4; k++) {
                float lo = (fmaxf(accL[n][k], 0.f) - mLa[k]) * scL[k] + bbLa[k];
                float hi = (fmaxf(accH[n][k], 0.f) - mHa[k]) * scH[k] + bbHa[k];
                po[k] = pack_bf2(lo, hi);
            }
            *(uint4*)&h1p[(size_t)i * 64 + c0] = o;
        }
    }
}

// ======== GINE2 gather: 4-edge batches, paired bf16 h1, CSR edge feats ========
__global__ void k_gine2_gather(const int* __restrict__ rowp,
                               const int* __restrict__ csr_ps,
                               const float* __restrict__ csr_e,
                               const float* __restrict__ edge_emb,
                               const float* __restrict__ W,   // [16,128]
                               const float* __restrict__ b,   // [128]
                               const unsigned* __restrict__ h1p,
                               float2* __restrict__ aggp) {
    int i = blockIdx.x * 4 + (threadIdx.x >> 6);
    int lane = threadIdx.x & 63;
    if (i >= N_NODES) return;
    v2f w01[12];
#pragma unroll
    for (int k = 0; k < 12; k++) {
        w01[k].x = W[(4 + k) * C_HID + lane];
        w01[k].y = W[(4 + k) * C_HID + lane + 64];
    }
    v2f tb01[4];
#pragma unroll
    for (int q = 0; q < 4; q++) {
        v2f t; t.x = b[lane]; t.y = b[lane + 64];
#pragma unroll
        for (int k = 0; k < 4; k++) {
            float ev = edge_emb[q * 4 + k];
            t.x += ev * W[k * C_HID + lane];
            t.y += ev * W[k * C_HID + lane + 64];
        }
        tb01[q] = t;
    }
    const v2f zero = v2(0.f);
    int beg = rfl(rowp[i]), end = rfl(rowp[i + 1]);
    v2f acc01 = zero;
    int p = beg;
    for (; p + 4 <= end; p += 4) {
        int ps4[4];
        float4 A[4], B[4], C4[4];
        v2f xs[4];
#pragma unroll
        for (int bq = 0; bq < 4; bq++) {
            const float4* ec4 = (const float4*)(csr_e + (size_t)(p + bq) * 12);
            A[bq] = ec4[0]; B[bq] = ec4[1]; C4[bq] = ec4[2];
            ps4[bq] = rfl(csr_ps[p + bq]);
            xs[bq] = unpack_bf2(h1p[(size_t)(ps4[bq] & 0xFFFFFF) * 64 + lane]);
        }
#pragma unroll
        for (int bq = 0; bq < 4; bq++) {
            int cat = ps4[bq] >> 24;
            v2f t = sel4v(cat, tb01[0], tb01[1], tb01[2], tb01[3]);
            t = __builtin_elementwise_fma(v2(A[bq].x), w01[0], t);
            t = __builtin_elementwise_fma(v2(A[bq].y), w01[1], t);
            t = __builtin_elementwise_fma(v2(A[bq].z), w01[2], t);
            t = __builtin_elementwise_fma(v2(A[bq].w), w01[3], t);
            t = __builtin_elementwise_fma(v2(B[bq].x), w01[4], t);
            t = __builtin_elementwise_fma(v2(B[bq].y), w01[5], t);
            t = __builtin_elementwise_fma(v2(B[bq].z), w01[6], t);
            t = __builtin_elementwise_fma(v2(B[bq].w), w01[7], t);
            t = __builtin_elementwise_fma(v2(C4[bq].x), w01[8], t);
            t = __builtin_elementwise_fma(v2(C4[bq].y), w01[9], t);
            t = __builtin_elementwise_fma(v2(C4[bq].z), w01[10], t);
            t = __builtin_elementwise_fma(v2(C4[bq].w), w01[11], t);
            acc01 += __builtin_elementwise_max(xs[bq] + t, zero);
        }
    }
    for (; p < end; ++p) {
        int ps = rfl(csr_ps[p]);
        int src = ps & 0xFFFFFF, cat = ps >> 24;
        const float4* ec4 = (const float4*)(csr_e + (size_t)p * 12);
        float4 A = ec4[0], B = ec4[1], C4 = ec4[2];
        v2f xs = unpack_bf2(h1p[(size_t)src * 64 + lane]);
        v2f t = sel4v(cat, tb01[0], tb01[1], tb01[2], tb01[3]);
        t = __builtin_elementwise_fma(v2(A.x), w01[0], t);
        t = __builtin_elementwise_fma(v2(A.y), w01[1], t);
        t = __builtin_elementwise_fma(v2(A.z), w01[2], t);
        t = __builtin_elementwise_fma(v2(A.w), w01[3], t);
        t = __builtin_elementwise_fma(v2(B.x), w01[4], t);
        t = __builtin_elementwise_fma(v2(B.y), w01[5], t);
        t = __builtin_elementwise_fma(v2(B.z), w01[6], t);
        t = __builtin_elementwise_fma(v2(B.w), w01[7], t);
        t = __builtin_elementwise_fma(v2(C4.x), w01[8], t);
        t = __builtin_elementwise_fma(v2(C4.y), w01[9], t);
        t = __builtin_elementwise_fma(v2(C4.z), w01[10], t);
        t = __builtin_elementwise_fma(v2(C4.w), w01[11], t);
        acc01 += __builtin_elementwise_max(xs + t, zero);
    }
    float2 o; o.x = acc01.x; o.y = acc01.y;
    aggp[(size_t)i * 64 + lane] = o;
}

// ===== FUSED (MFMA): GINE2 node MLP+BN -> h2 in LDS (bf16) -> GAT xl/xr.
// xr now ALSO stored as paired bf16 (in the dead x region) — halves the
// xr write + sequential re-read in k_gat_fused. =====
__global__ __launch_bounds__(256, 4) void k_gine2_gat0(
        const unsigned* __restrict__ h1p, const float2* __restrict__ aggp,
        const float* __restrict__ eps_p,
        const ushort* __restrict__ wtb,   // [3][128n][128k] bf16: W2n^T, Wl^T, Wr^T
        const float* __restrict__ b, const float* __restrict__ g,
        const float* __restrict__ bb, const float* __restrict__ bnm,
        const float* __restrict__ bnv,
        const float* __restrict__ bl, const float* __restrict__ br,
        const float* __restrict__ ea_sum, const float* __restrict__ edge_emb,
        const float* __restrict__ We,
        unsigned* __restrict__ xlp, unsigned* __restrict__ xrq,
        float* __restrict__ ee_loop) {
    __shared__ ushort zb[DT_NT * ZSTR];   // 8.7 KB  z (bf16)
    __shared__ ushort hb[DT_NT * ZSTR];   // 8.7 KB  h2 (bf16)
    int tid = threadIdx.x;
    int node0 = blockIdx.x * DT_NT;
    if (blockIdx.x == 0 && tid < C_HID) {
        const float inv = 1.f / (float)N_EDGES;
        float acc = 0.f;
#pragma unroll
        for (int k = 0; k < 4; k++) {
            float s = 0.f;
#pragma unroll
            for (int q = 0; q < 4; q++) s += ea_sum[12 + q] * edge_emb[q * 4 + k];
            acc += (s * inv) * We[k * C_HID + tid];
        }
#pragma unroll
        for (int k = 0; k < 12; k++)
            acc += (ea_sum[k] * inv) * We[(4 + k) * C_HID + tid];
        ee_loop[tid] = acc;
    }
    // --- phase 1: z = (1+eps)*h1 + agg -> bf16 zb ---
    {
        int nmax = min(DT_NT, N_NODES - node0);
        float s = 1.f + eps_p[0];
        for (int t = tid; t < nmax * 64; t += 256) {
            int n = t >> 6, pp = t & 63;
            v2f h = unpack_bf2(h1p[(size_t)(node0 + n) * 64 + pp]);
            float2 a = aggp[(size_t)(node0 + n) * 64 + pp];
            unsigned pk = pack_bf2(s * h.x + a.x, s * h.y + a.y);
            zb[n * ZSTR + pp]      = (ushort)(pk & 0xFFFFu);
            zb[n * ZSTR + pp + 64] = (ushort)(pk >> 16);
        }
    }
    __syncthreads();
    int lane = tid & 63;
    int w = tid >> 6;            // wave 0..3
    int lo4 = lane & 15, hi4 = lane >> 4;
    int mt = w & 1;              // m-tile (rows mt*16..mt*16+15)
    // --- phase 2: h2 = BN(ReLU(z @ W2n + b)) -> bf16 hb ---
    {
        int ntbase = (w >> 1) * 4;
        const ushort* zrow = &zb[(mt * 16 + lo4) * ZSTR + hi4 * 8];
        s8v afr[4];
#pragma unroll
        for (int ks = 0; ks < 4; ks++) afr[ks] = *(const s8v*)(zrow + ks * 32);
#pragma unroll
        for (int j = 0; j < 4; j++) {
            int nt = ntbase + j;
            int n = nt * 16 + lo4;
            const ushort* wrow = wtb + (size_t)n * 128 + hi4 * 8;
            f4v acc = {0.f, 0.f, 0.f, 0.f};
#pragma unroll
            for (int ks = 0; ks < 4; ks++) {
                s8v bfr = *(const s8v*)(wrow + ks * 32);
                acc = __builtin_amdgcn_mfma_f32_16x16x32_bf16(afr[ks], bfr, acc, 0, 0, 0);
            }
            float bnb = b[n];
            float sc = g[n] * rsqrtf(bnv[n] + BN_EPS);
            float mu = bnm[n], be = bb[n];
#pragma unroll
            for (int r = 0; r < 4; r++) {
                int mrow = mt * 16 + hi4 * 4 + r;
                float h2v = (fmaxf(acc[r] + bnb, 0.f) - mu) * sc + be;
                hb[mrow * ZSTR + n] = bf16r(h2v);
            }
        }
    }
    __syncthreads();
    // --- phase 3: xl = h2@Wl + bl (bf16 pairs), xr = h2@Wr + br (bf16 pairs) ---
    {
        int pg = w >> 1;         // pair group: cols pg*32..pg*32+31 (+64 partners)
        const ushort* hrow = &hb[(mt * 16 + lo4) * ZSTR + hi4 * 8];
        s8v afr[4];
#pragma unroll
        for (int ks = 0; ks < 4; ks++) afr[ks] = *(const s8v*)(hrow + ks * 32);
        for (int wsel = 0; wsel < 2; wsel++) {
            const ushort* wt = wtb + (size_t)(1 + wsel) * C_HID * C_HID;
            const float* bm = wsel ? br : bl;
            unsigned* dst = wsel ? xrq : xlp;
            f4v accA[2], accB[2];
#pragma unroll
            for (int j = 0; j < 2; j++) {
                int cA = (pg * 2 + j) * 16 + lo4;
                const ushort* wrA = wt + (size_t)cA * 128 + hi4 * 8;
                const ushort* wrB = wt + (size_t)(cA + 64) * 128 + hi4 * 8;
                f4v aA = {0.f, 0.f, 0.f, 0.f}, aB = {0.f, 0.f, 0.f, 0.f};
#pragma unroll
                for (int ks = 0; ks < 4; ks++) {
                    s8v bA = *(const s8v*)(wrA + ks * 32);
                    s8v bB = *(const s8v*)(wrB + ks * 32);
                    aA = __builtin_amdgcn_mfma_f32_16x16x32_bf16(afr[ks], bA, aA, 0, 0, 0);
                    aB = __builtin_amdgcn_mfma_f32_16x16x32_bf16(afr[ks], bB, aB, 0, 0, 0);
                }
                accA[j] = aA; accB[j] = aB;
            }
#pragma unroll
            for (int j = 0; j < 2; j++) {
                int c = (pg * 2 + j) * 16 + lo4;
                float blo = bm[c], bhi = bm[c + 64];
#pragma unroll
                for (int r = 0; r < 4; r++) {
                    int i = node0 + mt * 16 + hi4 * 4 + r;
                    if (i < N_NODES) {
                        float lo = accA[j][r] + blo, hi = accB[j][r] + bhi;
                        dst[(size_t)i * 64 + c] = pack_bf2(lo, hi);
                    }
                }
            }
        }
    }
}

// ===== GAT fused: 4-edge batches, CSR edge feats, merge-network softmax =====
__global__ void k_gat_fused(const int* __restrict__ rowp,
                            const int* __restrict__ csr_ps,
                            const float* __restrict__ csr_e,
                            const float* __restrict__ edge_emb,
                            const float* __restrict__ We,    // [16,128]
                            const float* __restrict__ att,   // [128]
                            const float* __restrict__ ee_loop,
                            const unsigned* __restrict__ xlp,
                            const unsigned* __restrict__ xrq,
                            const float* __restrict__ bias,  // [64]
                            float* __restrict__ out) {
    int i = blockIdx.x * 4 + (threadIdx.x >> 6);
    int lane = threadIdx.x & 63;
    if (i >= N_NODES) return;
    v2f w01[12];
#pragma unroll
    for (int k = 0; k < 12; k++) {
        w01[k].x = We[(4 + k) * C_HID + lane];
        w01[k].y = We[(4 + k) * C_HID + lane + 64];
    }
    v2f tb01[4];
#pragma unroll
    for (int q = 0; q < 4; q++) {
        v2f t = v2(0.f);
#pragma unroll
        for (int k = 0; k < 4; k++) {
            float ev = edge_emb[q * 4 + k];
            t.x += ev * We[k * C_HID + lane];
            t.y += ev * We[k * C_HID + lane + 64];
        }
        tb01[q] = t;
    }
    v2f at01; at01.x = att[lane]; at01.y = att[lane + 64];
    v2f lp01; lp01.x = ee_loop[lane]; lp01.y = ee_loop[lane + 64];
    const v2f zero = v2(0.f);
    const v2f fifth = v2(0.2f);

    v2f xr01 = unpack_bf2(xrq[(size_t)i * 64 + lane]);
    v2f xld01 = unpack_bf2(xlp[(size_t)i * 64 + lane]);

    // self-loop alpha (plain exp — alphas bounded, fp32-safe; verified R8)
    v2f z01 = xld01 + xr01 + lp01;
    z01 = __builtin_elementwise_max(z01, zero) +
          fifth * __builtin_elementwise_min(z01, zero);
    v2f d01 = z01 * at01;
    // 2-value merge reduce: even lanes hold sum(x), odd lanes sum(y)
    {
        float mq = merge_pair(d01.x, d01.y, 1);
        mq += __shfl_xor(mq, 2);
        mq += __shfl_xor(mq, 4);
        mq += __shfl_xor(mq, 8);
        mq += __shfl_xor(mq, 16);
        mq += __shfl_xor(mq, 32);
        int emqi = __float_as_int(__expf(mq));
        d01.x = __int_as_float(__builtin_amdgcn_readlane(emqi, 0));
        d01.y = __int_as_float(__builtin_amdgcn_readlane(emqi, 1));
    }
    v2f den01 = d01;
    v2f acc01 = xld01 * den01;

    int beg = rfl(rowp[i]), end = rfl(rowp[i + 1]);
    int p = beg;
    for (; p + 4 <= end; p += 4) {
        int ps4[4];
        float4 A[4], B[4], C4[4];
        v2f xs[4];
#pragma unroll
        for (int bq = 0; bq < 4; bq++) {
            const float4* ec4 = (const float4*)(csr_e + (size_t)(p + bq) * 12);
            A[bq] = ec4[0]; B[bq] = ec4[1]; C4[bq] = ec4[2];
            ps4[bq] = rfl(csr_ps[p + bq]);
            xs[bq] = unpack_bf2(xlp[(size_t)(ps4[bq] & 0xFFFFFF) * 64 + lane]);
        }
        v2f dd[4];
#pragma unroll
        for (int bq = 0; bq < 4; bq++) {
            int cat = ps4[bq] >> 24;
            v2f e = sel4v(cat, tb01[0], tb01[1], tb01[2], tb01[3]);
            e = __builtin_elementwise_fma(v2(A[bq].x), w01[0], e);
            e = __builtin_elementwise_fma(v2(A[bq].y), w01[1], e);
            e = __builtin_elementwise_fma(v2(A[bq].z), w01[2], e);
            e = __builtin_elementwise_fma(v2(A[bq].w), w01[3], e);
            e = __builtin_elementwise_fma(v2(B[bq].x), w01[4], e);
            e = __builtin_elementwise_fma(v2(B[bq].y), w01[5], e);
            e = __builtin_elementwise_fma(v2(B[bq].z), w01[6], e);
            e = __builtin_elementwise_fma(v2(B[bq].w), w01[7], e);
            e = __builtin_elementwise_fma(v2(C4[bq].x), w01[8], e);
            e = __builtin_elementwise_fma(v2(C4[bq].y), w01[9], e);
            e = __builtin_elementwise_fma(v2(C4[bq].z), w01[10], e);
            e = __builtin_elementwise_fma(v2(C4[bq].w), w01[11], e);
            v2f z = xs[bq] + xr01 + e;
            z = __builtin_elementwise_max(z, zero) +
                fifth * __builtin_elementwise_min(z, zero);
            dd[bq] = z * at01;
        }
        // 8-value merge-reduce network: after 3 merge + 3 butterfly stages,
        // lane l holds the full 64-lane sum of value (l&7).
        float m01 = merge_pair(dd[0].x, dd[0].y, 1);
        float m23 = merge_pair(dd[1].x, dd[1].y, 1);
        float m45 = merge_pair(dd[2].x, dd[2].y, 1);
        float m67 = merge_pair(dd[3].x, dd[3].y, 1);
        float n0 = merge_pair(m01, m23, 2);
        float n1 = merge_pair(m45, m67, 2);
        float q = merge_pair(n0, n1, 4);
        q += __shfl_xor(q, 8);
        q += __shfl_xor(q, 16);
        q += __shfl_xor(q, 32);
        int eqi = __float_as_int(__expf(q));   // one exp covers all 8 sums
        v2f p0, p1, p2, p3;
        p0.x = __int_as_float(__builtin_amdgcn_readlane(eqi, 0));
        p0.y = __int_as_float(__builtin_amdgcn_readlane(eqi, 1));
        p1.x = __int_as_float(__builtin_amdgcn_readlane(eqi, 2));
        p1.y = __int_as_float(__builtin_amdgcn_readlane(eqi, 3));
        p2.x = __int_as_float(__builtin_amdgcn_readlane(eqi, 4));
        p2.y = __int_as_float(__builtin_amdgcn_readlane(eqi, 5));
        p3.x = __int_as_float(__builtin_amdgcn_readlane(eqi, 6));
        p3.y = __int_as_float(__builtin_amdgcn_readlane(eqi, 7));
        den01 += (p0 + p1) + (p2 + p3);
        acc01 = __builtin_elementwise_fma(p0, xs[0], acc01);
        acc01 = __builtin_elementwise_fma(p1, xs[1], acc01);
        acc01 = __builtin_elementwise_fma(p2, xs[2], acc01);
        acc01 = __builtin_elementwise_fma(p3, xs[3], acc01);
    }
    for (; p < end; ++p) {
        int ps = rfl(csr_ps[p]);
        int src = ps & 0xFFFFFF, cat = ps >> 24;
        const float4* ec4 = (const float4*)(csr_e + (size_t)p * 12);
        float4 A = ec4[0], B = ec4[1], C4 = ec4[2];
        v2f xs = unpack_bf2(xlp[(size_t)src * 64 + lane]);
        v2f e = sel4v(cat, tb01[0], tb01[1], tb01[2], tb01[3]);
        e = __builtin_elementwise_fma(v2(A.x), w01[0], e);
        e = __builtin_elementwise_fma(v2(A.y), w01[1], e);
        e = __builtin_elementwise_fma(v2(A.z), w01[2], e);
        e = __builtin_elementwise_fma(v2(A.w), w01[3], e);
        e = __builtin_elementwise_fma(v2(B.x), w01[4], e);
        e = __builtin_elementwise_fma(v2(B.y), w01[5], e);
        e = __builtin_elementwise_fma(v2(B.z), w01[6], e);
        e = __builtin_elementwise_fma(v2(B.w), w01[7], e);
        e = __builtin_elementwise_fma(v2(C4.x), w01[8], e);
        e = __builtin_elementwise_fma(v2(C4.y), w01[9], e);
        e = __builtin_elementwise_fma(v2(C4.z), w01[10], e);
        e = __builtin_elementwise_fma(v2(C4.w), w01[11], e);
        v2f z = xs + xr01 + e;
        z = __builtin_elementwise_max(z, zero) +
            fifth * __builtin_elementwise_min(z, zero);
        v2f a = z * at01;
        float mq = merge_pair(a.x, a.y, 1);
        mq += __shfl_xor(mq, 2);
        mq += __shfl_xor(mq, 4);
        mq += __shfl_xor(mq, 8);
        mq += __shfl_xor(mq, 16);
        mq += __shfl_xor(mq, 32);
        int emqi = __float_as_int(__expf(mq));
        v2f pe;
        pe.x = __int_as_float(__builtin_amdgcn_readlane(emqi, 0));
        pe.y = __int_as_float(__builtin_amdgcn_readlane(emqi, 1));
        den01 += pe;
        acc01 = __builtin_elementwise_fma(pe, xs, acc01);
    }
    out[(size_t)i * C_OUT + lane] =
        0.5f * (acc01.x / den01.x + acc01.y / den01.y) + bias[lane];
}

extern "C" void kernel_launch(void* const* d_in, const int* in_sizes, int n_in,
                              void* d_out, int out_size, void* d_ws, size_t ws_size,
                              hipStream_t stream) {
    const int*   x_cat    = (const int*)d_in[0];
    const float* x_cont   = (const float*)d_in[1];
    const int*   e_cat    = (const int*)d_in[2];
    const float* e_cont   = (const float*)d_in[3];
    const int*   ei       = (const int*)d_in[4];
    const float* node_emb = (const float*)d_in[5];
    const float* edge_emb = (const float*)d_in[6];
    const float* eps1     = (const float*)d_in[7];
    const float* W1e      = (const float*)d_in[8];
    const float* b1e      = (const float*)d_in[9];
    const float* W1n      = (const float*)d_in[10];
    const float* b1n      = (const float*)d_in[11];
    const float* g1       = (const float*)d_in[12];
    const float* bb1      = (const float*)d_in[13];
    const float* m1       = (const float*)d_in[14];
    const float* v1       = (const float*)d_in[15];
    const float* eps2     = (const float*)d_in[16];
    const float* W2e      = (const float*)d_in[17];
    const float* b2e      = (const float*)d_in[18];
    const float* W2n      = (const float*)d_in[19];
    const float* b2n      = (const float*)d_in[20];
    const float* g2       = (const float*)d_in[21];
    const float* bb2      = (const float*)d_in[22];
    const float* m2       = (const float*)d_in[23];
    const float* v2p      = (const float*)d_in[24];
    const float* Wl       = (const float*)d_in[25];
    const float* bl       = (const float*)d_in[26];
    const float* Wr       = (const float*)d_in[27];
    const float* br       = (const float*)d_in[28];
    const float* Weg      = (const float*)d_in[29];
    const float* att      = (const float*)d_in[30];
    const float* gbias    = (const float*)d_in[31];

    const size_t NF128 = (size_t)N_NODES * C_HID;

    // layout: A (fp32 x; later reused for packed-bf16 xr) | B (agg36/agg-pairs) |
    //         Hb (bf16 pairs) | ea_sum | ee_loop | wtb (bf16 weights) | csr_e | meta
    float* A = (float*)d_ws;                 // N*128 floats
    float* B = A + NF128;                    // N*128 floats
    unsigned* Hb = (unsigned*)(B + NF128);   // N*64 u32
    float* ea_sum  = (float*)(Hb + (size_t)N_NODES * 64);   // 16
    float* ee_loop = ea_sum + 16;            // 128
    ushort* wtb  = (ushort*)(ee_loop + C_HID);              // 3*128*128 bf16
    float* csr_e = (float*)(wtb + 3 * C_HID * C_HID);       // E*12 floats (16B aligned)
    int* csr_ps  = (int*)(csr_e + (size_t)N_EDGES * 12);    // E
    int* deg     = csr_ps + N_EDGES;         // N
    int* cursor  = deg + N_NODES;            // N
    int* rowp    = cursor + N_NODES;         // N+1
    int* bsum    = rowp + N_NODES + 1;       // SB_N
    int* boff    = bsum + SB_N;              // SB_N

    float* x = A;
    float* agg36 = B;
    float2* aggp = (float2*)B;    // N*64 float2
    unsigned* xrq = (unsigned*)A; // packed bf16 xr; x is dead after k_gine1_node
    unsigned* h1p = Hb; unsigned* xlp = Hb;

    size_t need = (size_t)((char*)(boff + SB_N) - (char*)d_ws);
    if (ws_size < need) return;

    hipMemsetAsync(deg, 0, N_NODES * sizeof(int), stream);
    hipMemsetAsync(ea_sum, 0, 16 * sizeof(float), stream);

    const int EB = (N_EDGES + 255) / 256;
    const int NB4 = (N_NODES + 3) / 4;
    const int NBD = (N_NODES + DT_NT - 1) / DT_NT;
    const int WB = (3 * C_HID * C_HID + 255) / 256;

    k_wconv<<<WB, 256, 0, stream>>>(W2n, Wl, Wr, wtb);
    k_prep<<<NF_BLOCKS + DEG_BLOCKS + EAS_BLOCKS, 256, 0, stream>>>(
        x_cat, x_cont, node_emb, ei, e_cat, e_cont, x, deg, ea_sum);
    k_scan1<<<SB_N, SB_T, 0, stream>>>(deg, bsum);
    k_scan2<<<1, 128, 0, stream>>>(bsum, boff, rowp);
    k_scan3<<<SB_N, SB_T, 0, stream>>>(deg, boff, rowp, cursor);
    k_fill<<<EB, 256, 0, stream>>>(ei, e_cat, e_cont, cursor, csr_ps, csr_e);

    k_gine1_gather<<<NB4, 256, 0, stream>>>(
        rowp, csr_ps, csr_e, edge_emb, W1e, b1e, x, agg36);
    k_gine1_node<<<NBD, 256, 0, stream>>>(
        x, agg36, eps1, W1n, b1n, g1, bb1, m1, v1, h1p);
    k_gine2_gather<<<NB4, 256, 0, stream>>>(
        rowp, csr_ps, csr_e, edge_emb, W2e, b2e, h1p, aggp);

    k_gine2_gat0<<<NBD, 256, 0, stream>>>(
        h1p, aggp, eps2, wtb, b2n, g2, bb2, m2, v2p,
        bl, br, ea_sum, edge_emb, Weg, xlp, xrq, ee_loop);

    k_gat_fused<<<NB4, 256, 0, stream>>>(
        rowp, csr_ps, csr_e, edge_emb, Weg, att, ee_loop,
        xlp, xrq, gbias, (float*)d_out);
}